// Round 1
// baseline (7006.021 us; speedup 1.0000x reference)
//
#include <hip/hip_runtime.h>

#define B_   32
#define CIN  256
#define COUT 256
#define H_   56
#define W_   56

// grid: (14 h-blocks, COUT, B), block: (64, 4)
// Each thread: one output pixel (w = tid.x, h = blk.x*4 + tid.y) for one co.
// Whole block shares co -> mask gating is block-uniform: scale==0 blocks
// write zeros and exit (skips ~half the FLOPs, wave-uniform, no divergence).
__global__ __launch_bounds__(256) void binconv_naive(
    const float* __restrict__ x,
    const float* __restrict__ wgt,
    const float* __restrict__ mask,
    float* __restrict__ out) {
  const int w  = threadIdx.x;                  // 0..63, active < 56
  const int h  = blockIdx.x * 4 + threadIdx.y; // 0..55
  const int co = blockIdx.y;
  const int b  = blockIdx.z;

  const float m = mask[co];
  // w' = weight * (sign(m)+1)/2  ->  scale in {0, 0.5, 1}
  const float scale = (m > 0.f) ? 1.f : ((m < 0.f) ? 0.f : 0.5f);

  const size_t obase = (((size_t)b * COUT + co) * H_ + h) * W_ + w;
  if (scale == 0.f) {
    if (w < W_) out[obase] = 0.f;
    return;
  }

  const float* __restrict__ xb = x   + (size_t)b  * CIN * H_ * W_;
  const float* __restrict__ wc = wgt + (size_t)co * CIN * 9;

  float acc = 0.f;
  for (int ci = 0; ci < CIN; ++ci) {
    const float* __restrict__ xc = xb + (size_t)ci * (H_ * W_);
    const float* __restrict__ wk = wc + ci * 9;
    // hoist the 9 weights (wave-uniform -> scalar loads)
    float wv[9];
    #pragma unroll
    for (int t = 0; t < 9; ++t) wv[t] = wk[t];

    #pragma unroll
    for (int kh = 0; kh < 3; ++kh) {
      const int hh = h + kh - 1;
      if (hh < 0 || hh >= H_) continue;
      const float* __restrict__ xr = xc + hh * W_;
      #pragma unroll
      for (int kw = 0; kw < 3; ++kw) {
        const int ww = w + kw - 1;
        float xv = (ww >= 0 && ww < W_) ? xr[ww] : 0.f;
        // sign(x): +1 / -1 / 0 (keep sign(0)=0 exact like jnp.sign)
        float s = (xv > 0.f) ? 1.f : ((xv < 0.f) ? -1.f : 0.f);
        acc += s * wv[kh * 3 + kw];
      }
    }
  }

  if (w < W_) out[obase] = acc * scale;
}

extern "C" void kernel_launch(void* const* d_in, const int* in_sizes, int n_in,
                              void* d_out, int out_size, void* d_ws, size_t ws_size,
                              hipStream_t stream) {
  const float* x    = (const float*)d_in[0];
  const float* wgt  = (const float*)d_in[1];
  const float* mask = (const float*)d_in[2];
  float* out = (float*)d_out;

  dim3 grid(H_ / 4, COUT, B_);
  dim3 block(64, 4, 1);
  hipLaunchKernelGGL(binconv_naive, grid, block, 0, stream, x, wgt, mask, out);
}

// Round 4
// 249.755 us; speedup vs baseline: 28.0516x; 28.0516x over previous
//
#include <hip/hip_runtime.h>

#define B_    32
#define CIN   256
#define COUT  256
#define Hh    56
#define Ww    56
#define HP    58
#define WP    58
#define Kk    2304   // 9 taps * 256 ci, k = tap*256 + ci
#define BK    32
#define NKT   72     // Kk / BK

#define XPAD_ELEMS ((size_t)B_*HP*WP*CIN)   // 27,557,888 bf16
#define XPAD_GUARD 4096                      // wp-overrun guard (reads only)
#define AW_OFF_BYTES ((XPAD_ELEMS + XPAD_GUARD)*2)
#define WS_REQUIRED (AW_OFF_BYTES + (size_t)COUT*Kk*2)

using short8 = __attribute__((ext_vector_type(8))) short;
using f32x4  = __attribute__((ext_vector_type(4))) float;

__device__ __forceinline__ unsigned short f2bf(float f) {
  union { float f; unsigned u; } v; v.f = f;
  unsigned r = v.u + 0x7FFF + ((v.u >> 16) & 1);   // RNE
  return (unsigned short)(r >> 16);
}

__device__ __forceinline__ void gload_lds16(const void* g, void* l) {
  __builtin_amdgcn_global_load_lds(
      (const __attribute__((address_space(1))) unsigned int*)g,
      (__attribute__((address_space(3))) unsigned int*)l, 16, 0, 0);
}

// ---- prepass: gated weights -> bf16 A'[co][tap*256+ci], grid=256, block=256
__global__ __launch_bounds__(256) void prep_w(const float* __restrict__ wgt,
                                              const float* __restrict__ mask,
                                              unsigned short* __restrict__ aw) {
  __shared__ float buf[Kk];
  const int co = blockIdx.x, t = threadIdx.x;
  const float m = mask[co];
  const float sc = m > 0.f ? 1.f : (m < 0.f ? 0.f : 0.5f);
  const float* wc = wgt + (size_t)co * Kk;        // [ci][tap] order (9 per ci)
  for (int i = t; i < Kk; i += 256) buf[i] = wc[i] * sc;
  __syncthreads();
  unsigned short* ac = aw + (size_t)co * Kk;
  for (int o = t; o < Kk; o += 256) {
    int tap = o >> 8, ci = o & 255;
    ac[o] = f2bf(buf[ci * 9 + tap]);
  }
}

// ---- prepass: sign(x) -> bf16, zero-pad, NCHW -> [b][hp][wp][ci]
// grid=(HP, B_), block=256
__global__ __launch_bounds__(256) void prep_x(const float* __restrict__ x,
                                              unsigned short* __restrict__ xpad) {
  const int hp = blockIdx.x, b = blockIdx.y, t = threadIdx.x;
  unsigned* orow = (unsigned*)(xpad + (size_t)(b * HP + hp) * WP * CIN); // 7424 u32
  if (hp == 0 || hp == HP - 1) {
    for (int i = t; i < WP * CIN / 2; i += 256) orow[i] = 0u;
    return;
  }
  __shared__ unsigned short tile[WP][CIN + 2];   // +2 pad: conflict-free cols
  const int h = hp - 1;
  tile[0][t] = 0; tile[WP - 1][t] = 0;           // wp borders, t covers all ci
  const int tx = t & 63, ty = t >> 6;
  if (tx < Ww) {
    const float* xr = x + ((size_t)b * CIN * Hh + h) * Ww;   // + ci*Hh*Ww + tx
    for (int ci = ty; ci < CIN; ci += 4) {
      float xv = xr[(size_t)ci * Hh * Ww + tx];
      unsigned short s = (xv > 0.f) ? 0x3F80 : (xv < 0.f ? 0xBF80 : 0);
      tile[1 + tx][ci] = s;
    }
  }
  __syncthreads();
  for (int i = t; i < WP * CIN / 2; i += 256) {
    int o = i * 2, wp = o >> 8, ci = o & 255;
    orow[i] = *(const unsigned*)&tile[wp][ci];
  }
}

// ---- main: implicit GEMM, 128x128 tile, BK=32, 4 waves, mfma 16x16x32 bf16
// grid=(896 n-blocks = b*28+hb, 2 m-blocks), block=256
__global__ __launch_bounds__(256) void gemm_bin(
    const unsigned short* __restrict__ xpad,
    const unsigned short* __restrict__ aw,
    float* __restrict__ out) {
  __shared__ short lds[2 * 4096];      // A [128][32] | B [128][32], 16 KB
  short* lA = lds;
  short* lB = lds + 4096;

  const int t = threadIdx.x;
  const int nb = blockIdx.x;
  const int b  = nb / 28;
  const int h0 = (nb % 28) * 2;
  const int co0 = blockIdx.y * 128;

  const int wv = t >> 6, lane = t & 63;
  const int wm = wv & 1, wn = wv >> 1;       // wave tile: rows wm*64, cols wn*64
  const int lr = lane >> 4, lc = lane & 15;

  f32x4 acc[4][4] = {};

  const size_t xb = (size_t)b * HP;

  for (int kt = 0; kt < NKT; ++kt) {
    const int tap = kt >> 3, ci0 = (kt & 7) * 32;
    const int kh = tap / 3, kw = tap % 3;
    // stage A tile [128 co][32 k]
    #pragma unroll
    for (int i = 0; i < 2; ++i) {
      int idx = i * 256 + t;
      int row = idx >> 2, ch = idx & 3;
      gload_lds16(aw + (size_t)(co0 + row) * Kk + kt * BK + ch * 8, lA + idx * 8);
    }
    // stage B tile [128 n][32 k]  (n = r*64 + w, r in {0,1})
    #pragma unroll
    for (int i = 0; i < 2; ++i) {
      int idx = i * 256 + t;
      int n = idx >> 2, ch = idx & 3;
      int hp = h0 + (n >> 6) + kh;
      int wp = (n & 63) + kw;                 // may overrun row: guard handles
      gload_lds16(xpad + ((xb + hp) * WP + wp) * CIN + ci0 + ch * 8, lB + idx * 8);
    }
    __syncthreads();   // compiler drains vmcnt(0) before s_barrier
    short8 af[4], bf[4];
    #pragma unroll
    for (int m = 0; m < 4; ++m)
      af[m] = *(const short8*)&lA[(wm * 64 + m * 16 + lc) * BK + lr * 8];
    #pragma unroll
    for (int n = 0; n < 4; ++n)
      bf[n] = *(const short8*)&lB[(wn * 64 + n * 16 + lc) * BK + lr * 8];
    #pragma unroll
    for (int m = 0; m < 4; ++m)
      #pragma unroll
      for (int n = 0; n < 4; ++n)
        acc[m][n] = __builtin_amdgcn_mfma_f32_16x16x32_bf16(af[m], bf[n], acc[m][n], 0, 0, 0);
    __syncthreads();
  }

  // epilogue: C/D map col=lane&15, row=(lane>>4)*4+reg
  const int h = h0 + wn;
  #pragma unroll
  for (int nf = 0; nf < 4; ++nf) {
    int w = nf * 16 + lc;
    if (w >= Ww) continue;
    #pragma unroll
    for (int m = 0; m < 4; ++m) {
      int cobase = co0 + wm * 64 + m * 16 + lr * 4;
      #pragma unroll
      for (int r = 0; r < 4; ++r)
        out[((size_t)(b * COUT + cobase + r) * Hh + h) * Ww + w] = acc[m][nf][r];
    }
  }
}

// ---- fallback: proven-correct naive direct conv (used only if ws too small)
__global__ __launch_bounds__(256) void binconv_naive(
    const float* __restrict__ x,
    const float* __restrict__ wgt,
    const float* __restrict__ mask,
    float* __restrict__ out) {
  const int w  = threadIdx.x;
  const int h  = blockIdx.x * 4 + threadIdx.y;
  const int co = blockIdx.y;
  const int b  = blockIdx.z;

  const float m = mask[co];
  const float scale = (m > 0.f) ? 1.f : ((m < 0.f) ? 0.f : 0.5f);

  const size_t obase = (((size_t)b * COUT + co) * Hh + h) * Ww + w;
  if (scale == 0.f) {
    if (w < Ww) out[obase] = 0.f;
    return;
  }

  const float* __restrict__ xb = x   + (size_t)b  * CIN * Hh * Ww;
  const float* __restrict__ wc = wgt + (size_t)co * CIN * 9;

  float acc = 0.f;
  for (int ci = 0; ci < CIN; ++ci) {
    const float* __restrict__ xc = xb + (size_t)ci * (Hh * Ww);
    const float* __restrict__ wk = wc + ci * 9;
    float wv[9];
    #pragma unroll
    for (int t2 = 0; t2 < 9; ++t2) wv[t2] = wk[t2];
    #pragma unroll
    for (int kh = 0; kh < 3; ++kh) {
      const int hh = h + kh - 1;
      if (hh < 0 || hh >= Hh) continue;
      const float* __restrict__ xr = xc + hh * Ww;
      #pragma unroll
      for (int kw = 0; kw < 3; ++kw) {
        const int ww = w + kw - 1;
        float xv = (ww >= 0 && ww < Ww) ? xr[ww] : 0.f;
        float s = (xv > 0.f) ? 1.f : ((xv < 0.f) ? -1.f : 0.f);
        acc += s * wv[kh * 3 + kw];
      }
    }
  }
  if (w < Ww) out[obase] = acc * scale;
}

extern "C" void kernel_launch(void* const* d_in, const int* in_sizes, int n_in,
                              void* d_out, int out_size, void* d_ws, size_t ws_size,
                              hipStream_t stream) {
  const float* x    = (const float*)d_in[0];
  const float* wgt  = (const float*)d_in[1];
  const float* mask = (const float*)d_in[2];
  float* out = (float*)d_out;

  if (ws_size < WS_REQUIRED) {
    // workspace too small for implicit-GEMM staging: safe fallback
    hipLaunchKernelGGL(binconv_naive, dim3(Hh / 4, COUT, B_), dim3(64, 4, 1),
                       0, stream, x, wgt, mask, out);
    return;
  }

  unsigned short* xpad = (unsigned short*)d_ws;
  unsigned short* aw   = (unsigned short*)((char*)d_ws + AW_OFF_BYTES);

  hipLaunchKernelGGL(prep_w, dim3(COUT), dim3(256), 0, stream, wgt, mask, aw);
  hipLaunchKernelGGL(prep_x, dim3(HP, B_), dim3(256), 0, stream, x, xpad);
  hipLaunchKernelGGL(gemm_bin, dim3(896, 2), dim3(256), 0, stream, xpad, aw, out);
}

// Round 6
// 160.924 us; speedup vs baseline: 43.5362x; 1.5520x over previous
//
#include <hip/hip_runtime.h>

#define B_    32
#define CIN   256
#define COUT  256
#define Hh    56
#define Ww    56
#define HP    58
#define WP    58
#define Kk    2304   // 9 taps * 256 ci, k = tap*256 + ci
#define NT    36     // K-tiles of BK=64 (4 per tap)

#define XPAD_ELEMS ((size_t)B_*HP*WP*CIN)   // 27,557,888 bf16
#define XPAD_GUARD 4096                      // wp-overrun guard (reads only)
#define AW_OFF_BYTES ((XPAD_ELEMS + XPAD_GUARD)*2)
#define WS_REQUIRED (AW_OFF_BYTES + (size_t)COUT*Kk*2)

using short8 = __attribute__((ext_vector_type(8))) short;
using f32x4  = __attribute__((ext_vector_type(4))) float;

__device__ __forceinline__ unsigned short f2bf(float f) {
  union { float f; unsigned u; } v; v.f = f;
  unsigned r = v.u + 0x7FFF + ((v.u >> 16) & 1);   // RNE
  return (unsigned short)(r >> 16);
}

__device__ __forceinline__ void gload_lds16(const void* g, void* l) {
  __builtin_amdgcn_global_load_lds(
      (const __attribute__((address_space(1))) unsigned int*)g,
      (__attribute__((address_space(3))) unsigned int*)l, 16, 0, 0);
}

// ---- prepass: gated weights -> bf16 A'[co][tap*256+ci], grid=256, block=256
__global__ __launch_bounds__(256) void prep_w(const float* __restrict__ wgt,
                                              const float* __restrict__ mask,
                                              unsigned short* __restrict__ aw) {
  __shared__ float buf[Kk];
  const int co = blockIdx.x, t = threadIdx.x;
  const float m = mask[co];
  const float sc = m > 0.f ? 1.f : (m < 0.f ? 0.f : 0.5f);
  const float* wc = wgt + (size_t)co * Kk;        // [ci][tap] order (9 per ci)
  for (int i = t; i < Kk; i += 256) buf[i] = wc[i] * sc;
  __syncthreads();
  unsigned short* ac = aw + (size_t)co * Kk;
  for (int o = t; o < Kk; o += 256) {
    int tap = o >> 8, ci = o & 255;
    ac[o] = f2bf(buf[ci * 9 + tap]);
  }
}

// ---- prepass: sign(x) -> bf16, zero-pad, NCHW -> [b][hp][wp][ci]
// grid=(HP, B_), block=256
__global__ __launch_bounds__(256) void prep_x(const float* __restrict__ x,
                                              unsigned short* __restrict__ xpad) {
  const int hp = blockIdx.x, b = blockIdx.y, t = threadIdx.x;
  unsigned* orow = (unsigned*)(xpad + (size_t)(b * HP + hp) * WP * CIN); // 7424 u32
  if (hp == 0 || hp == HP - 1) {
    for (int i = t; i < WP * CIN / 2; i += 256) orow[i] = 0u;
    return;
  }
  __shared__ unsigned short tile[WP][CIN + 2];   // +2 pad: conflict-free cols
  const int h = hp - 1;
  tile[0][t] = 0; tile[WP - 1][t] = 0;           // wp borders, t covers all ci
  const int tx = t & 63, ty = t >> 6;
  if (tx < Ww) {
    const float* xr = x + ((size_t)b * CIN * Hh + h) * Ww;   // + ci*Hh*Ww + tx
    for (int ci = ty; ci < CIN; ci += 4) {
      float xv = xr[(size_t)ci * Hh * Ww + tx];
      unsigned short s = (xv > 0.f) ? 0x3F80 : (xv < 0.f ? 0xBF80 : 0);
      tile[1 + tx][ci] = s;
    }
  }
  __syncthreads();
  for (int i = t; i < WP * CIN / 2; i += 256) {
    int o = i * 2, wp = o >> 8, ci = o & 255;
    orow[i] = *(const unsigned*)&tile[wp][ci];
  }
}

// ---- main: 256x256 tile, BK=64, 8 waves, 8-phase schedule w/ counted vmcnt.
// LDS per K-tile buffer (64KB): A = [2 ks][256 co][32 bf16], B same at +32KB.
// Swizzle: physical colb holds logical colb ^ (((row>>3)&1)<<5)  (st_16x32).
// grid=(448 = b*14 + hblk), block=512 (8 waves: wm=wid>>2, wn=wid&3)
__global__ __launch_bounds__(512, 2) void gemm_bin256(
    const unsigned short* __restrict__ xpad,
    const unsigned short* __restrict__ aw,
    float* __restrict__ out) {
  extern __shared__ char smem[];

  const int t = threadIdx.x;
  const int nb = blockIdx.x;
  const int b = nb / 14, hblk = nb % 14;
  const int h0 = hblk * 4;

  const int wid = t >> 6, lane = t & 63;
  const int wm = wid >> 2, wn = wid & 3;     // wave tile: 128 M x 64 N
  const int lc = lane & 15, lr = lane >> 4;
  const int sw = ((lc >> 3) & 1) << 5;       // row-bit-3 == lc-bit-3

  // fragment read bases (per-lane, swizzled)
  const char* aptr = smem + (size_t)(wm * 128 + lc) * 64 + ((lr * 16) ^ sw);
  const char* bptr = smem + 32768 + (size_t)(wn * 64 + lc) * 64 + ((lr * 16) ^ sw);

  // staging invariants: physical colb = (t&3)*16, its row-bit-3 = (t>>5)&1
  const int colbp = ((t & 3) << 4) ^ (((t >> 5) & 1) << 5);
  const unsigned short* awp0 = aw + (size_t)(t >> 2) * Kk + (colbp >> 1);
  const unsigned short* awp1 = aw + (size_t)(128 + (t >> 2)) * Kk + (colbp >> 1);
  const size_t xb = (size_t)b * HP;
  const unsigned short* xbp0 =
      xpad + ((xb + h0 + (t >> 8)) * WP + ((t >> 2) & 63)) * CIN + (colbp >> 1);
  const unsigned short* xbp1 =
      xpad + ((xb + h0 + 2 + (t >> 8)) * WP + ((t >> 2) & 63)) * CIN + (colbp >> 1);
  char* ldst = smem + t * 16;

  short8 af[4], bf[4];
  f32x4 acc[8][4] = {};

#define STAGE_A(ktx, ks, BUF) do {                                             \
    gload_lds16(awp0 + (ktx) * 64 + (ks) * 32,                                 \
                ldst + (BUF) * 65536 + (ks) * 16384);                          \
    gload_lds16(awp1 + (ktx) * 64 + (ks) * 32,                                 \
                ldst + (BUF) * 65536 + (ks) * 16384 + 8192);                   \
  } while (0)

#define STAGE_B(ktx, ks, BUF) do {                                             \
    int tap_ = (ktx) >> 2;                                                     \
    int kh_ = tap_ / 3, kw_ = tap_ - kh_ * 3;                                  \
    int off_ = (kh_ * WP + kw_) * CIN + ((ktx) & 3) * 64 + (ks) * 32;          \
    gload_lds16(xbp0 + off_, ldst + (BUF) * 65536 + 32768 + (ks) * 16384);     \
    gload_lds16(xbp1 + off_, ldst + (BUF) * 65536 + 32768 + (ks) * 16384 + 8192); \
  } while (0)

#define READ_A(mh, BUF, ks) do { _Pragma("unroll")                             \
    for (int i_ = 0; i_ < 4; ++i_)                                             \
      af[i_] = *(const short8*)(aptr + (BUF) * 65536 + (ks) * 16384 +          \
                                ((mh) * 4 + i_) * 1024);                       \
  } while (0)

#define READ_B(BUF, ks) do { _Pragma("unroll")                                 \
    for (int i_ = 0; i_ < 4; ++i_)                                             \
      bf[i_] = *(const short8*)(bptr + (BUF) * 65536 + (ks) * 16384 + i_ * 1024); \
  } while (0)

#define MFMA_Q(mh) do { _Pragma("unroll")                                      \
    for (int m_ = 0; m_ < 4; ++m_) { _Pragma("unroll")                         \
      for (int n_ = 0; n_ < 4; ++n_)                                           \
        acc[(mh) * 4 + m_][n_] = __builtin_amdgcn_mfma_f32_16x16x32_bf16(      \
            af[m_], bf[n_], acc[(mh) * 4 + m_][n_], 0, 0, 0); }                \
  } while (0)

#define BAR()  __builtin_amdgcn_s_barrier()
#define SFENCE() __builtin_amdgcn_sched_barrier(0)

#define KTILE(kt, BUF) do {                                                    \
    const int kn1_ = ((kt) + 1 < NT) ? (kt) + 1 : NT - 1;                      \
    const int kn2_ = ((kt) + 2 < NT) ? (kt) + 2 : NT - 1;                      \
    /* P1: quadrant (ks0, m-half0) */                                          \
    READ_A(0, BUF, 0); READ_B(BUF, 0);                                         \
    STAGE_A(kn1_, 1, (BUF) ^ 1);                                               \
    BAR(); SFENCE();                                                           \
    __builtin_amdgcn_s_setprio(1); MFMA_Q(0); __builtin_amdgcn_s_setprio(0);   \
    BAR(); SFENCE();                                                           \
    /* P2: (ks0, m-half1) */                                                   \
    READ_A(1, BUF, 0);                                                         \
    STAGE_B(kn1_, 1, (BUF) ^ 1);                                               \
    BAR(); SFENCE();                                                           \
    __builtin_amdgcn_s_setprio(1); MFMA_Q(1); __builtin_amdgcn_s_setprio(0);   \
    BAR(); SFENCE();                                                           \
    /* P3: (ks1, m-half0) */                                                   \
    READ_A(0, BUF, 1); READ_B(BUF, 1);                                         \
    STAGE_A(kn2_, 0, BUF);                                                     \
    BAR(); SFENCE();                                                           \
    __builtin_amdgcn_s_setprio(1); MFMA_Q(0); __builtin_amdgcn_s_setprio(0);   \
    BAR(); SFENCE();                                                           \
    /* P4: (ks1, m-half1) */                                                   \
    READ_A(1, BUF, 1);                                                         \
    STAGE_B(kn2_, 0, BUF);                                                     \
    BAR(); SFENCE();                                                           \
    __builtin_amdgcn_s_setprio(1); MFMA_Q(1); __builtin_amdgcn_s_setprio(0);   \
    asm volatile("s_waitcnt vmcnt(4)" ::: "memory");                           \
    SFENCE();                                                                  \
    BAR(); SFENCE();                                                           \
  } while (0)

  // prologue: kt0 all 4 halves + kt1 ks0 halves (12 loads), wait oldest 8
  STAGE_A(0, 0, 0);
  STAGE_B(0, 0, 0);
  STAGE_A(0, 1, 0);
  STAGE_B(0, 1, 0);
  STAGE_A(1, 0, 1);
  STAGE_B(1, 0, 1);
  asm volatile("s_waitcnt vmcnt(4)" ::: "memory");
  SFENCE();
  BAR(); SFENCE();

#pragma unroll 1
  for (int it = 0; it < NT / 2; ++it) {
    KTILE(2 * it, 0);
    KTILE(2 * it + 1, 1);
  }

  // drain any in-flight LDS-DMA before LDS is deallocated at endpgm
  asm volatile("s_waitcnt vmcnt(0)" ::: "memory");

  // epilogue: C/D map col(n-dim)=lane&15, row(m-dim)=(lane>>4)*4+reg
  const int h = h0 + wn;
  #pragma unroll
  for (int m = 0; m < 8; ++m) {
    const int co = wm * 128 + m * 16 + lr * 4;
    #pragma unroll
    for (int n = 0; n < 4; ++n) {
      const int w = n * 16 + lc;
      if (w < Ww) {
        #pragma unroll
        for (int r = 0; r < 4; ++r)
          out[(((size_t)b * COUT + co + r) * Hh + h) * Ww + w] = acc[m][n][r];
      }
    }
  }
}

// ---- fallback: proven-correct naive direct conv (used only if ws too small)
__global__ __launch_bounds__(256) void binconv_naive(
    const float* __restrict__ x,
    const float* __restrict__ wgt,
    const float* __restrict__ mask,
    float* __restrict__ out) {
  const int w  = threadIdx.x;
  const int h  = blockIdx.x * 4 + threadIdx.y;
  const int co = blockIdx.y;
  const int b  = blockIdx.z;

  const float m = mask[co];
  const float scale = (m > 0.f) ? 1.f : ((m < 0.f) ? 0.f : 0.5f);

  const size_t obase = (((size_t)b * COUT + co) * Hh + h) * Ww + w;
  if (scale == 0.f) {
    if (w < Ww) out[obase] = 0.f;
    return;
  }

  const float* __restrict__ xb = x   + (size_t)b  * CIN * Hh * Ww;
  const float* __restrict__ wc = wgt + (size_t)co * CIN * 9;

  float acc = 0.f;
  for (int ci = 0; ci < CIN; ++ci) {
    const float* __restrict__ xc = xb + (size_t)ci * (Hh * Ww);
    const float* __restrict__ wk = wc + ci * 9;
    float wv[9];
    #pragma unroll
    for (int t2 = 0; t2 < 9; ++t2) wv[t2] = wk[t2];
    #pragma unroll
    for (int kh = 0; kh < 3; ++kh) {
      const int hh = h + kh - 1;
      if (hh < 0 || hh >= Hh) continue;
      const float* __restrict__ xr = xc + hh * Ww;
      #pragma unroll
      for (int kw = 0; kw < 3; ++kw) {
        const int ww = w + kw - 1;
        float xv = (ww >= 0 && ww < Ww) ? xr[ww] : 0.f;
        float s = (xv > 0.f) ? 1.f : ((xv < 0.f) ? -1.f : 0.f);
        acc += s * wv[kh * 3 + kw];
      }
    }
  }
  if (w < Ww) out[obase] = acc * scale;
}

extern "C" void kernel_launch(void* const* d_in, const int* in_sizes, int n_in,
                              void* d_out, int out_size, void* d_ws, size_t ws_size,
                              hipStream_t stream) {
  const float* x    = (const float*)d_in[0];
  const float* wgt  = (const float*)d_in[1];
  const float* mask = (const float*)d_in[2];
  float* out = (float*)d_out;

  bool ok = ws_size >= WS_REQUIRED;
  if (ok) {
    hipError_t e = hipFuncSetAttribute(
        (const void*)gemm_bin256, hipFuncAttributeMaxDynamicSharedMemorySize,
        131072);
    ok = (e == hipSuccess);
  }
  if (!ok) {
    hipLaunchKernelGGL(binconv_naive, dim3(Hh / 4, COUT, B_), dim3(64, 4, 1),
                       0, stream, x, wgt, mask, out);
    return;
  }

  unsigned short* xpad = (unsigned short*)d_ws;
  unsigned short* aw   = (unsigned short*)((char*)d_ws + AW_OFF_BYTES);

  hipLaunchKernelGGL(prep_w, dim3(COUT), dim3(256), 0, stream, wgt, mask, aw);
  hipLaunchKernelGGL(prep_x, dim3(HP, B_), dim3(256), 0, stream, x, xpad);
  hipLaunchKernelGGL(gemm_bin256, dim3(448), dim3(512), 131072, stream,
                     xpad, aw, out);
}